// Round 8
// baseline (553.080 us; speedup 1.0000x reference)
//
#include <hip/hip_runtime.h>
#include <hip/hip_bf16.h>

#define HIDDEN 2048
#define INNER  1024
#define NE     64
#define TOPK   8
#define NTOK   512

typedef float f32x4 __attribute__((ext_vector_type(4)));
typedef short bf16x8 __attribute__((ext_vector_type(8)));

static __device__ __forceinline__ unsigned short b16(float f) {
  return __builtin_bit_cast(unsigned short, __float2bfloat16(f));
}
static __device__ __forceinline__ unsigned int pk2(float lo, float hi) {
  return (unsigned)b16(lo) | ((unsigned)b16(hi) << 16);
}

// ---- gating: xconv + out-zero + gate dot + topk; last block does scan+scatter ----
__global__ __launch_bounds__(256) void gating_kernel(
    const float* __restrict__ x, const float* __restrict__ gw, const float* __restrict__ gb,
    int* __restrict__ ticket, int* __restrict__ counts, int* __restrict__ offsets,
    int* __restrict__ topk_e, float* __restrict__ topk_w,
    int* __restrict__ perm_tok, float* __restrict__ perm_wt,
    unsigned short* __restrict__ xb, float* __restrict__ out) {
  const int t = blockIdx.x;
  const int tid = threadIdx.x;
  const int lane = tid & 63, w = tid >> 6;

  // fused: x -> bf16, zero out row (atomic accumulation target)
  {
    const float4* xi = (const float4*)(x + (size_t)t * HIDDEN);
    float4 v0 = xi[tid * 2], v1 = xi[tid * 2 + 1];
    ushort4 o0, o1;
    o0.x = b16(v0.x); o0.y = b16(v0.y); o0.z = b16(v0.z); o0.w = b16(v0.w);
    o1.x = b16(v1.x); o1.y = b16(v1.y); o1.z = b16(v1.z); o1.w = b16(v1.w);
    ushort4* xo = (ushort4*)(xb + (size_t)t * HIDDEN);
    xo[tid * 2] = o0; xo[tid * 2 + 1] = o1;
    f32x4 z = (f32x4)0.f;
    f32x4* orow = (f32x4*)(out + (size_t)t * HIDDEN);
    orow[tid * 2] = z; orow[tid * 2 + 1] = z;
  }

  // gate logits: one quad per expert
  const int e = tid >> 2, seg = tid & 3;
  const f32x4* gr = (const f32x4*)(gw + (size_t)e * HIDDEN);
  const f32x4* xr = (const f32x4*)(x + (size_t)t * HIDDEN);
  float acc = 0.f;
  #pragma unroll 8
  for (int k = 0; k < 128; ++k) {
    int idx = k * 4 + seg;
    f32x4 a = xr[idx], b = gr[idx];
    acc += a.x * b.x + a.y * b.y + a.z * b.z + a.w * b.w;
  }
  acc += __shfl_xor(acc, 1);
  acc += __shfl_xor(acc, 2);
  __shared__ float sP[NE];
  if (seg == 0) sP[e] = acc;
  __syncthreads();

  __shared__ float sW[TOPK];
  __shared__ int   sE[TOPK];
  if (w == 0) {
    float logit = gb[lane] + sP[lane];
    float m = logit;
    #pragma unroll
    for (int off = 32; off; off >>= 1) m = fmaxf(m, __shfl_xor(m, off));
    float p = __expf(logit - m);
    float s = p;
    #pragma unroll
    for (int off = 32; off; off >>= 1) s += __shfl_xor(s, off);
    p /= s;
    float myp = p;
    #pragma unroll
    for (int k = 0; k < TOPK; ++k) {
      float v = myp; int ei = lane;
      #pragma unroll
      for (int off = 32; off; off >>= 1) {
        float v2 = __shfl_xor(v, off); int e2 = __shfl_xor(ei, off);
        if (v2 > v || (v2 == v && e2 < ei)) { v = v2; ei = e2; }
      }
      if (lane == 0) { sW[k] = v; sE[k] = ei; }
      if (lane == ei) myp = -1.0f;
    }
  }
  __syncthreads();
  if (tid < TOPK) {
    float ss = 0.f;
    #pragma unroll
    for (int k = 0; k < TOPK; ++k) ss += sW[k];
    topk_e[t * TOPK + tid] = sE[tid];
    topk_w[t * TOPK + tid] = sW[tid] / ss;
  }

  __threadfence();
  __syncthreads();
  __shared__ int slast;
  if (tid == 0) {
    int old = atomicAdd(ticket, 1);
    slast = (old == (int)gridDim.x - 1);
  }
  __syncthreads();
  if (!slast) return;
  __threadfence();

  __shared__ int hcnt[NE], soff[NE], ccur[NE];
  if (tid < NE) hcnt[tid] = 0;
  __syncthreads();
  for (int i = tid; i < NTOK * TOPK; i += 256) atomicAdd(&hcnt[topk_e[i]], 1);
  __syncthreads();
  if (tid < NE) {
    int c = hcnt[tid];
    int s = c;
    #pragma unroll
    for (int off = 1; off < 64; off <<= 1) {
      int o = __shfl_up(s, off);
      if (tid >= off) s += o;
    }
    soff[tid] = s - c; ccur[tid] = 0;
    counts[tid] = c; offsets[tid] = s - c;
  }
  __syncthreads();
  for (int i = tid; i < NTOK * TOPK; i += 256) {
    int ee = topk_e[i];
    int p = atomicAdd(&ccur[ee], 1);
    int pos = soff[ee] + p;
    perm_tok[pos] = i >> 3;
    perm_wt[pos] = topk_w[i];
  }
}

// ---- fused expert kernel: block = (expert e, inner chunk q of 128) ----
// phase1: act[128 tok x 128 inner] = gelu(x@w1g^T)*(x@w1u^T), act stays in LDS
// phase2: for 16 n-tiles of 128 output cols: out[tok] += wt * act @ w2slice^T
// LDS: [2][A1 8KB + B1 16KB] dbuf (48KB) at 0 ... act 32KB at 49152. phase2
// reuses [0,32768) for the w2 dbuf. Total 80KB -> fits alongside nothing else.
__global__ __launch_bounds__(512, 2) void fused_kernel(
    const unsigned short* __restrict__ xb, const float* __restrict__ w1,
    const float* __restrict__ w2,
    const int* __restrict__ offsets, const int* __restrict__ counts,
    const int* __restrict__ perm_tok, const float* __restrict__ perm_wt,
    float* __restrict__ out) {
  const int e = blockIdx.x >> 3, q = blockIdx.x & 7;
  const int n_e = counts[e];
  if (n_e == 0) return;
  const int off = offsets[e];
  const int tid = threadIdx.x;
  const int lane = tid & 63, wave = tid >> 6;
  const int u2 = lane >> 4, l15 = lane & 15;
  const int wm = (wave & 1) * 64;        // M group (tokens)
  const int wn = (wave >> 1) * 32;       // N group (32 cols within 128)

  __shared__ uint4 smem4[81920 / 16];
  char* smem = (char*)smem4;
  __shared__ int   stok[128];
  __shared__ float swt[128];

  // phase1 staging maps
  const int arow = tid >> 2, aslot = tid & 3;            // A: 128 rows x 4x16B
  const int brow = tid >> 1, bh = tid & 1;               // B: 256 rows x 2 halves
  const int asw = (arow >> 1) & 3;
  const int bsw = (brow >> 1) & 3;
  const float* w1g = w1 + ((size_t)e * 2 * INNER + (size_t)q * 128) * HIDDEN;
  const float* brptr = (brow < 128)
      ? w1g + (size_t)brow * HIDDEN
      : w1g + ((size_t)INNER + (brow - 128)) * HIDDEN;

  // phase2 staging map (R5-proven pattern): 4 rows/thread, 256B contig per row
  const int r32 = tid >> 4, l16 = tid & 15;
  const int bidx0 = r32 * 16 + (((l16 >> 1) ^ (r32 & 7)) << 1) + (l16 & 1);  // uint2 units
  const float* w2q = w2 + (size_t)e * HIDDEN * INNER + (size_t)q * 128;

  for (int m0 = 0; m0 < n_e; m0 += 128) {
    __syncthreads();
    if (tid < 128) {
      int idx = m0 + tid;
      int cl = idx < n_e ? idx : n_e - 1;
      stok[tid] = perm_tok[off + cl];
      swt[tid] = perm_wt[off + cl];
    }
    __syncthreads();

    // ================= phase 1 =================
    const unsigned short* axrow = xb + (size_t)stok[arow] * HIDDEN;
    uint4 a_r = ((const uint4*)axrow)[aslot];
    f32x4 b_r0, b_r1, b_r2, b_r3;
    {
      const f32x4* bp = (const f32x4*)brptr;
      b_r0 = bp[bh]; b_r1 = bp[bh + 2]; b_r2 = bp[bh + 4]; b_r3 = bp[bh + 6];
    }

    f32x4 ag[4][2], au[4][2];
    #pragma unroll
    for (int i = 0; i < 4; ++i)
      #pragma unroll
      for (int j = 0; j < 2; ++j) { ag[i][j] = (f32x4)0.f; au[i][j] = (f32x4)0.f; }

    for (int k0 = 0; k0 < HIDDEN; k0 += 32) {
      char* buf = smem + ((k0 >> 5) & 1) * 24576;
      uint4* A1 = (uint4*)buf;
      char*  B1 = buf + 8192;
      A1[arow * 4 + (aslot ^ asw)] = a_r;
      *(uint2*)(B1 + brow * 64 + ((0 ^ bsw) << 4) + bh * 8) =
          make_uint2(pk2(b_r0.x, b_r0.y), pk2(b_r0.z, b_r0.w));
      *(uint2*)(B1 + brow * 64 + ((1 ^ bsw) << 4) + bh * 8) =
          make_uint2(pk2(b_r1.x, b_r1.y), pk2(b_r1.z, b_r1.w));
      *(uint2*)(B1 + brow * 64 + ((2 ^ bsw) << 4) + bh * 8) =
          make_uint2(pk2(b_r2.x, b_r2.y), pk2(b_r2.z, b_r2.w));
      *(uint2*)(B1 + brow * 64 + ((3 ^ bsw) << 4) + bh * 8) =
          make_uint2(pk2(b_r3.x, b_r3.y), pk2(b_r3.z, b_r3.w));
      __syncthreads();
      int k1 = k0 + 32;
      if (k1 < HIDDEN) {
        a_r = ((const uint4*)(axrow + k1))[aslot];
        const f32x4* bp = (const f32x4*)(brptr + k1);
        b_r0 = bp[bh]; b_r1 = bp[bh + 2]; b_r2 = bp[bh + 4]; b_r3 = bp[bh + 6];
      }
      bf16x8 af[4], bg[2], bu[2];
      #pragma unroll
      for (int mi = 0; mi < 4; ++mi) {
        int r = wm + mi * 16 + l15;
        af[mi] = __builtin_bit_cast(bf16x8, A1[r * 4 + (u2 ^ ((r >> 1) & 3))]);
      }
      #pragma unroll
      for (int ni = 0; ni < 2; ++ni) {
        int rg = wn + ni * 16 + l15;
        int sw = u2 ^ ((rg >> 1) & 3);
        bg[ni] = __builtin_bit_cast(bf16x8, *(uint4*)(B1 + rg * 64 + (sw << 4)));
        bu[ni] = __builtin_bit_cast(bf16x8, *(uint4*)(B1 + (128 + rg) * 64 + (sw << 4)));
      }
      #pragma unroll
      for (int mi = 0; mi < 4; ++mi)
        #pragma unroll
        for (int ni = 0; ni < 2; ++ni) {
          ag[mi][ni] = __builtin_amdgcn_mfma_f32_16x16x32_bf16(af[mi], bg[ni], ag[mi][ni], 0, 0, 0);
          au[mi][ni] = __builtin_amdgcn_mfma_f32_16x16x32_bf16(af[mi], bu[ni], au[mi][ni], 0, 0, 0);
        }
    }

    // act epilogue: gelu(g)*u -> bf16 into act LDS [128 rows x 128 cols], swizzled
    {
      char* actb = smem + 49152;
      #pragma unroll
      for (int mi = 0; mi < 4; ++mi)
        #pragma unroll
        for (int ni = 0; ni < 2; ++ni)
          #pragma unroll
          for (int r4 = 0; r4 < 4; ++r4) {
            int row = wm + mi * 16 + u2 * 4 + r4;
            int col = wn + ni * 16 + l15;
            float g = ag[mi][ni][r4];
            float u = au[mi][ni][r4];
            float ge = g / (1.0f + __expf(-1.5957691216057308f * (g + 0.044715f * g * g * g)));
            int boff = row * 256 + (((col >> 3) ^ (row & 7)) << 4) + (col & 7) * 2;
            *(unsigned short*)(actb + boff) = b16(ge * u);
          }
    }
    __syncthreads();

    // ================= phase 2 =================
    f32x4 w_r0, w_r1, w_r2, w_r3;
    {
      const float* p0 = w2q + (size_t)r32 * INNER + l16 * 4;   // n0=0, kk=0
      w_r0 = *(const f32x4*)(p0);
      w_r1 = *(const f32x4*)(p0 + (size_t)32 * INNER);
      w_r2 = *(const f32x4*)(p0 + (size_t)64 * INNER);
      w_r3 = *(const f32x4*)(p0 + (size_t)96 * INNER);
    }
    f32x4 acc[4][2];
    char* actb = smem + 49152;

    for (int j = 0; j < 32; ++j) {
      const int kk = j & 1, n0 = (j >> 1) * 128;
      char* buf2 = smem + (j & 1) * 16384;
      uint2* B2 = (uint2*)buf2;
      B2[bidx0]        = make_uint2(pk2(w_r0.x, w_r0.y), pk2(w_r0.z, w_r0.w));
      B2[bidx0 + 512]  = make_uint2(pk2(w_r1.x, w_r1.y), pk2(w_r1.z, w_r1.w));
      B2[bidx0 + 1024] = make_uint2(pk2(w_r2.x, w_r2.y), pk2(w_r2.z, w_r2.w));
      B2[bidx0 + 1536] = make_uint2(pk2(w_r3.x, w_r3.y), pk2(w_r3.z, w_r3.w));
      __syncthreads();
      if (j + 1 < 32) {
        int kk1 = (j + 1) & 1, n01 = ((j + 1) >> 1) * 128;
        const float* pn = w2q + (size_t)(n01 + r32) * INNER + kk1 * 64 + l16 * 4;
        w_r0 = *(const f32x4*)(pn);
        w_r1 = *(const f32x4*)(pn + (size_t)32 * INNER);
        w_r2 = *(const f32x4*)(pn + (size_t)64 * INNER);
        w_r3 = *(const f32x4*)(pn + (size_t)96 * INNER);
      }
      if (kk == 0) {
        #pragma unroll
        for (int i = 0; i < 4; ++i)
          #pragma unroll
          for (int jj = 0; jj < 2; ++jj) acc[i][jj] = (f32x4)0.f;
      }
      #pragma unroll
      for (int ks = 0; ks < 2; ++ks) {
        bf16x8 af2[4], bf2[2];
        #pragma unroll
        for (int mi = 0; mi < 4; ++mi) {
          int r = wm + mi * 16 + l15;
          int slot = (kk * 8 + ks * 4 + u2) ^ (r & 7);
          af2[mi] = __builtin_bit_cast(bf16x8, *(uint4*)(actb + r * 256 + (slot << 4)));
        }
        #pragma unroll
        for (int ni = 0; ni < 2; ++ni) {
          int r = wn + ni * 16 + l15;
          int slot = (ks * 4 + u2) ^ (r & 7);
          bf2[ni] = __builtin_bit_cast(bf16x8, *(uint4*)(buf2 + r * 128 + (slot << 4)));
        }
        #pragma unroll
        for (int mi = 0; mi < 4; ++mi)
          #pragma unroll
          for (int ni = 0; ni < 2; ++ni)
            acc[mi][ni] = __builtin_amdgcn_mfma_f32_16x16x32_bf16(af2[mi], bf2[ni], acc[mi][ni], 0, 0, 0);
      }
      if (kk == 1) {
        #pragma unroll
        for (int mi = 0; mi < 4; ++mi)
          #pragma unroll
          for (int r4 = 0; r4 < 4; ++r4) {
            int mrow = wm + mi * 16 + u2 * 4 + r4;
            int m = m0 + mrow;
            if (m < n_e) {
              int tok = stok[mrow];
              float wt = swt[mrow];
              float* orow = out + (size_t)tok * HIDDEN + n0 + wn;
              #pragma unroll
              for (int ni = 0; ni < 2; ++ni)
                atomicAdd(&orow[ni * 16 + l15], wt * acc[mi][ni][r4]);
            }
          }
      }
    }
  }
}

extern "C" void kernel_launch(void* const* d_in, const int* in_sizes, int n_in,
                              void* d_out, int out_size, void* d_ws, size_t ws_size,
                              hipStream_t stream) {
  const float* x  = (const float*)d_in[0];
  const float* gw = (const float*)d_in[1];
  const float* gb = (const float*)d_in[2];
  const float* w1 = (const float*)d_in[3];
  const float* w2 = (const float*)d_in[4];
  float* out = (float*)d_out;

  char* ws = (char*)d_ws;
  int*   ticket   = (int*)(ws + 0x000);
  int*   counts   = (int*)(ws + 0x100);
  int*   offsets  = (int*)(ws + 0x200);
  int*   topk_e   = (int*)(ws + 0x1000);
  float* topk_w   = (float*)(ws + 0x5000);
  int*   perm_tok = (int*)(ws + 0x9000);
  float* perm_wt  = (float*)(ws + 0xD000);
  unsigned short* xb = (unsigned short*)(ws + 0x11000);   // 2 MB

  hipMemsetAsync(ticket, 0, 0x40, stream);

  gating_kernel<<<NTOK, 256, 0, stream>>>(x, gw, gb, ticket, counts, offsets,
                                          topk_e, topk_w, perm_tok, perm_wt, xb, out);
  fused_kernel<<<NE * 8, 512, 0, stream>>>(xb, w1, w2, offsets, counts,
                                           perm_tok, perm_wt, out);
}